// Round 14
// baseline (2469.111 us; speedup 1.0000x reference)
//
#include <hip/hip_runtime.h>
#include <math.h>

#define HD 128
#define NBR 8
#define LSTEPS 64
#define TILE_B 32
#define HT_PAD 36     // 144B rows: float4-aligned; GEMM h-reads are wave-uniform broadcasts
#define HRM_PAD 132   // row-major h rows
#define WS_PAD 132    // wsoft rows padded: conflict-free across lanes

// workspace layout (floats)
#define WPT_OFF   0        // w_hh permuted-transposed: [k][4*hh+q] = w_hh[q*128+hh][k]   (128*512)
#define WIPT_OFF  65536    // w_ih same layout                                            (128*512)
#define PP_OFF    131072   // P'' = w_emb@w_ih^T + bsum, layout [j][4*hh+q]               (8*512)
#define BSUM_OFF  135168   // (b_ih+b_hh) permuted [q*128+hh]                             (512)

__global__ __launch_bounds__(256) void setup_kernel(
    const float* __restrict__ w_emb, const float* __restrict__ w_ih,
    const float* __restrict__ w_hh, const float* __restrict__ b_ih,
    const float* __restrict__ b_hh, float* __restrict__ ws)
{
  int tid = blockIdx.x * blockDim.x + threadIdx.x;
  if (tid < 65536) {
    int k = tid >> 9, col = tid & 511;
    int hh = col >> 2, q = col & 3;
    ws[WPT_OFF + tid]  = w_hh[(q*HD + hh)*HD + k];
    ws[WIPT_OFF + tid] = w_ih[(q*HD + hh)*HD + k];
  }
  if (tid < 4096) {
    int j = tid >> 9, rem = tid & 511;
    int q = rem >> 7, hh2 = rem & 127;
    const float* wr = w_ih + (q*HD + hh2)*HD;
    const float* er = w_emb + j*HD;
    float s = 0.f;
    for (int k = 0; k < HD; ++k) s = fmaf(er[k], wr[k], s);
    ws[PP_OFF + (size_t)j*512 + 4*hh2 + q] = s + b_ih[q*HD + hh2] + b_hh[q*HD + hh2];
  }
  if (tid < 512) {
    int q = tid >> 7, hh2 = tid & 127;
    ws[BSUM_OFF + tid] = b_ih[q*HD + hh2] + b_hh[q*HD + hh2];
  }
}

__device__ __forceinline__ float fsig(float x) {
  return __fdividef(1.f, 1.f + __expf(-x));
}
__device__ __forceinline__ float ftanh(float x) {
  float ax = fabsf(x);
  float e  = __expf(-2.f * ax);
  float r  = __fdividef(1.f - e, 1.f + e);
  return copysignf(r, x);
}

// 16 batches per thread: 64 explicit-component FMAs for one k, h read inline from LDS
// (compiler schedules the ds_reads ahead and emits fine-grained lgkmcnt waits)
#define KFMA16L(W, HPTR) do { \
    float4 h0 = *(const float4*)(HPTR); \
    float4 h1 = *(const float4*)((HPTR) + 4); \
    float4 h2 = *(const float4*)((HPTR) + 8); \
    float4 h3 = *(const float4*)((HPTR) + 12); \
    acc[0][0]  = fmaf(h0.x, (W).x, acc[0][0]);  acc[0][1]  = fmaf(h0.y, (W).x, acc[0][1]);  \
    acc[0][2]  = fmaf(h0.z, (W).x, acc[0][2]);  acc[0][3]  = fmaf(h0.w, (W).x, acc[0][3]);  \
    acc[0][4]  = fmaf(h1.x, (W).x, acc[0][4]);  acc[0][5]  = fmaf(h1.y, (W).x, acc[0][5]);  \
    acc[0][6]  = fmaf(h1.z, (W).x, acc[0][6]);  acc[0][7]  = fmaf(h1.w, (W).x, acc[0][7]);  \
    acc[0][8]  = fmaf(h2.x, (W).x, acc[0][8]);  acc[0][9]  = fmaf(h2.y, (W).x, acc[0][9]);  \
    acc[0][10] = fmaf(h2.z, (W).x, acc[0][10]); acc[0][11] = fmaf(h2.w, (W).x, acc[0][11]); \
    acc[0][12] = fmaf(h3.x, (W).x, acc[0][12]); acc[0][13] = fmaf(h3.y, (W).x, acc[0][13]); \
    acc[0][14] = fmaf(h3.z, (W).x, acc[0][14]); acc[0][15] = fmaf(h3.w, (W).x, acc[0][15]); \
    acc[1][0]  = fmaf(h0.x, (W).y, acc[1][0]);  acc[1][1]  = fmaf(h0.y, (W).y, acc[1][1]);  \
    acc[1][2]  = fmaf(h0.z, (W).y, acc[1][2]);  acc[1][3]  = fmaf(h0.w, (W).y, acc[1][3]);  \
    acc[1][4]  = fmaf(h1.x, (W).y, acc[1][4]);  acc[1][5]  = fmaf(h1.y, (W).y, acc[1][5]);  \
    acc[1][6]  = fmaf(h1.z, (W).y, acc[1][6]);  acc[1][7]  = fmaf(h1.w, (W).y, acc[1][7]);  \
    acc[1][8]  = fmaf(h2.x, (W).y, acc[1][8]);  acc[1][9]  = fmaf(h2.y, (W).y, acc[1][9]);  \
    acc[1][10] = fmaf(h2.z, (W).y, acc[1][10]); acc[1][11] = fmaf(h2.w, (W).y, acc[1][11]); \
    acc[1][12] = fmaf(h3.x, (W).y, acc[1][12]); acc[1][13] = fmaf(h3.y, (W).y, acc[1][13]); \
    acc[1][14] = fmaf(h3.z, (W).y, acc[1][14]); acc[1][15] = fmaf(h3.w, (W).y, acc[1][15]); \
    acc[2][0]  = fmaf(h0.x, (W).z, acc[2][0]);  acc[2][1]  = fmaf(h0.y, (W).z, acc[2][1]);  \
    acc[2][2]  = fmaf(h0.z, (W).z, acc[2][2]);  acc[2][3]  = fmaf(h0.w, (W).z, acc[2][3]);  \
    acc[2][4]  = fmaf(h1.x, (W).z, acc[2][4]);  acc[2][5]  = fmaf(h1.y, (W).z, acc[2][5]);  \
    acc[2][6]  = fmaf(h1.z, (W).z, acc[2][6]);  acc[2][7]  = fmaf(h1.w, (W).z, acc[2][7]);  \
    acc[2][8]  = fmaf(h2.x, (W).z, acc[2][8]);  acc[2][9]  = fmaf(h2.y, (W).z, acc[2][9]);  \
    acc[2][10] = fmaf(h2.z, (W).z, acc[2][10]); acc[2][11] = fmaf(h2.w, (W).z, acc[2][11]); \
    acc[2][12] = fmaf(h3.x, (W).z, acc[2][12]); acc[2][13] = fmaf(h3.y, (W).z, acc[2][13]); \
    acc[2][14] = fmaf(h3.z, (W).z, acc[2][14]); acc[2][15] = fmaf(h3.w, (W).z, acc[2][15]); \
    acc[3][0]  = fmaf(h0.x, (W).w, acc[3][0]);  acc[3][1]  = fmaf(h0.y, (W).w, acc[3][1]);  \
    acc[3][2]  = fmaf(h0.z, (W).w, acc[3][2]);  acc[3][3]  = fmaf(h0.w, (W).w, acc[3][3]);  \
    acc[3][4]  = fmaf(h1.x, (W).w, acc[3][4]);  acc[3][5]  = fmaf(h1.y, (W).w, acc[3][5]);  \
    acc[3][6]  = fmaf(h1.z, (W).w, acc[3][6]);  acc[3][7]  = fmaf(h1.w, (W).w, acc[3][7]);  \
    acc[3][8]  = fmaf(h2.x, (W).w, acc[3][8]);  acc[3][9]  = fmaf(h2.y, (W).w, acc[3][9]);  \
    acc[3][10] = fmaf(h2.z, (W).w, acc[3][10]); acc[3][11] = fmaf(h2.w, (W).w, acc[3][11]); \
    acc[3][12] = fmaf(h3.x, (W).w, acc[3][12]); acc[3][13] = fmaf(h3.y, (W).w, acc[3][13]); \
    acc[3][14] = fmaf(h3.z, (W).w, acc[3][14]); acc[3][15] = fmaf(h3.w, (W).w, acc[3][15]); \
  } while (0)

// lgkm-only barrier: no vmcnt(0) drain (out-stores / w-prefetches stay in flight)
#define BAR_LGKM() asm volatile("s_waitcnt lgkmcnt(0)\n\ts_barrier" ::: "memory")

__global__ __launch_bounds__(256, 1) void ctrl_kernel(
    const int* __restrict__ class_ids,
    const float* __restrict__ gumbel_u,
    const float* __restrict__ g_emb,
    const float* __restrict__ w_soft,
    const float* __restrict__ ws,
    float* __restrict__ out,
    int Btot)
{
  __shared__ __align__(16) float hT[HD * HT_PAD];           // 18432 B (single buffer)
  __shared__ __align__(16) float h_rm[TILE_B * HRM_PAD];    // 16896 B (row-major h for sampling)
  __shared__ __align__(16) float wsoft_l[NBR * WS_PAD];     // 4224 B
  __shared__ __align__(16) float pp_l[NBR * 512];           // 16384 B
  __shared__ int br_l[TILE_B];                              // 128 B  (~56 KB -> 2 blocks/CU)

  const int tid = threadIdx.x;
  const int b0  = blockIdx.x * TILE_B;
  const size_t BL = (size_t)Btot * LSTEPS;

  const float* __restrict__ wpT  = ws + WPT_OFF;
  const float* __restrict__ wipT = ws + WIPT_OFF;

  // wsoft into padded LDS rows
  {
    int col = tid & 127, half = tid >> 7;
    #pragma unroll
    for (int rr = 0; rr < 4; ++rr)
      wsoft_l[(half*4 + rr)*WS_PAD + col] = w_soft[(half*4 + rr)*HD + col];
  }
  for (int i = tid; i < NBR*512; i += 256) pp_l[i] = ws[PP_OFF + i];

  const int hh = tid & 127;   // hidden/gate index (w cols 4*hh..4*hh+3)
  const int bg = tid >> 7;    // batch half: 0 -> batches 0..15, 1 -> 16..31
  const int sg = tid >> 3;    // sampling: batch group 0..31
  const int sr = tid & 7;     // sampling: branch nb owned by this lane

  // ---- stage x0^T = g_emb[class_ids]^T into hT ----
  {
    int sb = tid >> 3;        // 0..31 batch
    int kc = tid & 7;         // k-chunk of 16
    int cid = class_ids[b0 + sb];
    const float* src = g_emb + (size_t)cid * HD + kc*16;
    #pragma unroll
    for (int ii = 0; ii < 4; ++ii) {
      float4 v = *(const float4*)(src + 4*ii);
      int kb = kc*16 + 4*ii;
      hT[(kb+0)*HT_PAD + sb] = v.x;
      hT[(kb+1)*HT_PAD + sb] = v.y;
      hT[(kb+2)*HT_PAD + sb] = v.z;
      hT[(kb+3)*HT_PAD + sb] = v.w;
    }
  }
  __syncthreads();

  // ---- q0 = 0.5*(x0 @ w_ih^T + bsum) for 16 batches, plain registers ----
  float q0[4][16];
  {
    float acc[4][16];
    #pragma unroll
    for (int q = 0; q < 4; ++q)
      #pragma unroll
      for (int j = 0; j < 16; ++j) acc[q][j] = 0.f;

    const float* wr = wipT + 4*hh;
    const float* hr = hT + bg*16;
    #pragma unroll 2
    for (int k = 0; k < HD; ++k) {
      float4 w = *(const float4*)(wr);
      KFMA16L(w, hr);
      wr += 512; hr += HT_PAD;
    }
    #pragma unroll
    for (int q = 0; q < 4; ++q) {
      float bs = ws[BSUM_OFF + q*HD + hh];
      #pragma unroll
      for (int j = 0; j < 16; ++j)
        q0[q][j] = 0.5f * (acc[q][j] + bs);
    }
  }
  __syncthreads();

  float c[16];
  #pragma unroll
  for (int j = 0; j < 16; ++j) c[j] = 0.f;

  for (int t = 0; t < LSTEPS; ++t) {
    // ---- gumbel: 1 coalesced dword per lane; hidden under GEMM ----
    float uval = gumbel_u[((size_t)t * Btot + b0) * NBR + tid];

    // ---- acc starts at q0 (x0-part + bias pre-folded); GEMM adds h @ w_hh^T ----
    float acc[4][16];
    #pragma unroll
    for (int q = 0; q < 4; ++q)
      #pragma unroll
      for (int j = 0; j < 16; ++j) acc[q][j] = q0[q][j];

    if (t > 0) {
      __builtin_amdgcn_s_setprio(1);
      const float* wr = wpT + 4*hh;
      const float* hr = hT + bg*16;
      // rotation-free 4-k unrolled pipeline: two alternating NAMED w-pair sets.
      // Positional vmcnt works: X's loads are separated from X's use by Y's loads
      // + 128 FMAs (~290 issue-cyc > L2 latency). No loop-carried register copies.
      float4 wX0 = *(const float4*)(wr);            // w(0)
      float4 wX1 = *(const float4*)(wr + 512);      // w(1)
      #pragma unroll 1
      for (int i = 0; i < 31; ++i) {
        float4 wY0 = *(const float4*)(wr + 2*512);  // w(k+2)
        float4 wY1 = *(const float4*)(wr + 3*512);  // w(k+3)
        KFMA16L(wX0, hr);                           // k
        KFMA16L(wX1, hr + HT_PAD);                  // k+1
        wX0 = *(const float4*)(wr + 4*512);         // w(k+4)   (max 4*30+5=125 < 128)
        wX1 = *(const float4*)(wr + 5*512);         // w(k+5)
        KFMA16L(wY0, hr + 2*HT_PAD);                // k+2
        KFMA16L(wY1, hr + 3*HT_PAD);                // k+3
        wr += 4*512; hr += 4*HT_PAD;
      }
      // epilogue: k = 124..127 (no w prefetch past the end)
      {
        float4 wY0 = *(const float4*)(wr + 2*512);  // w(126)
        float4 wY1 = *(const float4*)(wr + 3*512);  // w(127)
        KFMA16L(wX0, hr);                           // k = 124
        KFMA16L(wX1, hr + HT_PAD);                  // k = 125
        KFMA16L(wY0, hr + 2*HT_PAD);                // k = 126
        KFMA16L(wY1, hr + 3*HT_PAD);                // k = 127
      }
      __builtin_amdgcn_s_setprio(0);
    }

    // (E) br_l(t-1) visible for combine; also: every wave's hT/h_rm reads of the
    // previous step are complete (they happened before this wave's GEMM), so the
    // writes below are race-free with a SINGLE hT buffer.
    BAR_LGKM();

    // ---- combine x-part, LSTM pointwise ----
    float h2v[16];
    #pragma unroll
    for (int j = 0; j < 16; ++j) {
      float gi, gf, gg, go;
      if (t == 0) {
        gi = 2.f*acc[0][j]; gf = 2.f*acc[1][j];
        gg = 2.f*acc[2][j]; go = 2.f*acc[3][j];
      } else {
        int br = br_l[bg*16 + j];
        float4 pv = *(const float4*)(&pp_l[br*512 + 4*hh]);
        gi = fmaf(0.5f, pv.x, acc[0][j]);
        gf = fmaf(0.5f, pv.y, acc[1][j]);
        gg = fmaf(0.5f, pv.z, acc[2][j]);
        go = fmaf(0.5f, pv.w, acc[3][j]);
      }
      float iv = fsig(gi);
      float fv = fsig(gf);
      float gv = ftanh(gg);
      float ov = fsig(go);
      float c2 = fmaf(fv, c[j], iv*gv);
      c[j] = c2;
      h2v[j] = ov * ftanh(c2);
    }

    // write h_{t+1}: transposed (for next GEMM) + row-major (for sampling)
    {
      float* dst = &hT[hh*HT_PAD + bg*16];
      *(float4*)(dst)    = make_float4(h2v[0], h2v[1], h2v[2], h2v[3]);
      *(float4*)(dst+4)  = make_float4(h2v[4], h2v[5], h2v[6], h2v[7]);
      *(float4*)(dst+8)  = make_float4(h2v[8], h2v[9], h2v[10],h2v[11]);
      *(float4*)(dst+12) = make_float4(h2v[12],h2v[13],h2v[14],h2v[15]);
      #pragma unroll
      for (int j = 0; j < 16; ++j)
        h_rm[(bg*16 + j)*HRM_PAD + hh] = h2v[j];
    }
    BAR_LGKM();   // (B) new h visible

    // ---- sampling: lane (sg, sr) owns branch sr of batch sg; fully in-lane dot ----
    {
      const float* hp  = h_rm + sg*HRM_PAD;      // broadcast across the 8 lanes of the group
      const float* wp2 = wsoft_l + sr*WS_PAD;    // conflict-free (132-pad)
      float p = 0.f;
      #pragma unroll
      for (int i = 0; i < 32; ++i) {
        float4 hv = *(const float4*)(hp + 4*i);
        float4 wv = *(const float4*)(wp2 + 4*i);
        p = fmaf(hv.x, wv.x, p); p = fmaf(hv.y, wv.y, p);
        p = fmaf(hv.z, wv.z, p); p = fmaf(hv.w, wv.w, p);
      }
      float lg = 2.5f * ftanh(p * 0.2f);
      float uc = fminf(fmaxf(uval, 1e-8f), 0.99999999f);
      float y  = lg - __logf(-__logf(uc));
      // argmax over the 8 lanes, first-occurrence tie-break (y desc, nb asc)
      int   bi = sr;
      float by = y;
      #pragma unroll
      for (int mk = 1; mk < 8; mk <<= 1) {
        float oy = __shfl_xor(by, mk, 64);
        int   ob = __shfl_xor(bi, mk, 64);
        if (oy > by || (oy == by && ob < bi)) { by = oy; bi = ob; }
      }
      // softmax stats across the 8 lanes
      float m = lg;
      #pragma unroll
      for (int mk = 1; mk < 8; mk <<= 1) m = fmaxf(m, __shfl_xor(m, mk, 64));
      float se = __expf(lg - m);
      #pragma unroll
      for (int mk = 1; mk < 8; mk <<= 1) se += __shfl_xor(se, mk, 64);
      float lse = __logf(se);
      float lpi = (lg - m) - lse;
      float ent = __expf(lpi) * lpi;
      #pragma unroll
      for (int mk = 1; mk < 8; mk <<= 1) ent += __shfl_xor(ent, mk, 64);
      ent = -ent;
      float lgbr = __shfl(lg, (tid & 56) + bi, 64);   // winner lane's logit
      float lp = (lgbr - m) - lse;
      if (sr == 0) {
        br_l[sg] = bi;
        size_t row = (size_t)(b0 + sg) * LSTEPS + t;
        out[row]        = (float)bi;
        out[BL + row]   = lp;
        out[2*BL + row] = ent;
        out[3*BL + row] = __expf(lp);
      }
    }
    // no barrier here: the next iteration's (E) barrier (after GEMM) orders
    // br_l writes before combine's reads, and h_rm reads before its overwrite.
  }
}

extern "C" void kernel_launch(void* const* d_in, const int* in_sizes, int n_in,
                              void* d_out, int out_size, void* d_ws, size_t ws_size,
                              hipStream_t stream) {
  const int*   class_ids = (const int*)d_in[0];
  const float* gumbel_u  = (const float*)d_in[1];
  const float* g_emb     = (const float*)d_in[2];
  const float* w_emb     = (const float*)d_in[3];
  const float* w_soft    = (const float*)d_in[4];
  const float* w_ih      = (const float*)d_in[5];
  const float* w_hh      = (const float*)d_in[6];
  const float* b_ih      = (const float*)d_in[7];
  const float* b_hh      = (const float*)d_in[8];
  float* out = (float*)d_out;
  float* ws  = (float*)d_ws;
  int B = in_sizes[0];

  hipLaunchKernelGGL(setup_kernel, dim3(256), dim3(256), 0, stream,
                     w_emb, w_ih, w_hh, b_ih, b_hh, ws);
  hipLaunchKernelGGL(ctrl_kernel, dim3(B / TILE_B), dim3(256), 0, stream,
                     class_ids, gumbel_u, g_emb, w_soft, ws, out, B);
}